// Round 3
// baseline (209.810 us; speedup 1.0000x reference)
//
#include <hip/hip_runtime.h>

// Seesaw_Conv: 3x3 conv (16->128) offsets -> scrambled bilinear sampling -> 9-tap weighted sum + residual
// B=4, C=16, H=W=192, KE=9, M=4
// ws layout: [0,73728): Wt[144][128]; [73728,+75497472): off pairs float2[64][4][192][192]
//   pair p = c2*4+m holds (off_x, off_y) for channel c2, offset m.

#define HH 192
#define WW 192
#define CC 16
#define CO 128

__global__ __launch_bounds__(256) void transpose_w_kernel(
    const float* __restrict__ Wref, float* __restrict__ Wt) {
  int i = blockIdx.x * 256 + threadIdx.x;
  if (i < CO * 144) {
    int o = i / 144, term = i - o * 144;
    Wt[term * CO + o] = Wref[i];
  }
}

// Direct conv, block = 4h x 64w x 64co, thread = 8w x 8co.  LDS B/FMA = 0.71 -> FMA-bound.
__global__ __launch_bounds__(256) void conv_kernel(
    const float* __restrict__ x, const float* __restrict__ Wt,
    const float* __restrict__ bref, float2* __restrict__ off2) {
  __shared__ float sW[144][64];    // 36.9 KB
  __shared__ float sX[16][6][66];  // 25.3 KB
  int bid = blockIdx.x;
  int ct = bid & 1;
  int wt_ = (bid >> 1) % 3;
  int hp = (bid / 6) % 48;
  int b  = bid / 288;
  int co0 = ct * 64, w0 = wt_ * 64, h0 = hp * 4;
  int t = threadIdx.x;
  for (int i = t; i < 144 * 64; i += 256) {
    int term = i >> 6, cl = i & 63;
    sW[term][cl] = Wt[term * CO + co0 + cl];
  }
  for (int i = t; i < 16 * 6 * 66; i += 256) {
    int cin = i / 396;
    int rem = i - cin * 396;
    int r = rem / 66;
    int wl2 = rem - r * 66;
    int gh = h0 + r - 1, gw = w0 + wl2 - 1;
    float v = 0.0f;
    if ((unsigned)gh < 192u && (unsigned)gw < 192u)
      v = x[((b * CC + cin) * HH + gh) * WW + gw];
    sX[cin][r][wl2] = v;
  }
  __syncthreads();
  int wg = t & 7, cg = (t >> 3) & 7, hr = t >> 6;
  int wl = wg * 8;
  float acc[8][8];  // [w][co]
  #pragma unroll
  for (int j = 0; j < 8; ++j)
    #pragma unroll
    for (int k = 0; k < 8; ++k) acc[j][k] = 0.0f;
  for (int cin = 0; cin < 16; ++cin) {
    #pragma unroll
    for (int kh = 0; kh < 3; ++kh) {
      const float* row = &sX[cin][hr + kh][0];
      float4 xa = *(const float4*)&row[wl];
      float4 xb = *(const float4*)&row[wl + 4];
      float2 xc = *(const float2*)&row[wl + 8];
      float xw[10] = {xa.x, xa.y, xa.z, xa.w, xb.x, xb.y, xb.z, xb.w, xc.x, xc.y};
      int term0 = (cin * 3 + kh) * 3;
      #pragma unroll
      for (int kw = 0; kw < 3; ++kw) {
        float4 wa = *(const float4*)&sW[term0 + kw][cg * 8];
        float4 wb = *(const float4*)&sW[term0 + kw][cg * 8 + 4];
        #pragma unroll
        for (int j = 0; j < 8; ++j) {
          float xv = xw[kw + j];
          acc[j][0] += xv * wa.x;  acc[j][1] += xv * wa.y;
          acc[j][2] += xv * wa.z;  acc[j][3] += xv * wa.w;
          acc[j][4] += xv * wb.x;  acc[j][5] += xv * wb.y;
          acc[j][6] += xv * wb.z;  acc[j][7] += xv * wb.w;
        }
      }
    }
  }
  float bias[8];
  #pragma unroll
  for (int i = 0; i < 8; ++i) bias[i] = bref[co0 + cg * 8 + i];
  int h = h0 + hr;
  int p0 = (co0 >> 1) + cg * 4;
  #pragma unroll
  for (int k = 0; k < 4; ++k) {
    float2* base = off2 + ((((size_t)(p0 + k) * 4 + b) * HH + h) * WW + w0 + wl);
    #pragma unroll
    for (int j2 = 0; j2 < 4; ++j2) {
      float4 v = {acc[2 * j2][2 * k] + bias[2 * k], acc[2 * j2][2 * k + 1] + bias[2 * k + 1],
                  acc[2 * j2 + 1][2 * k] + bias[2 * k], acc[2 * j2 + 1][2 * k + 1] + bias[2 * k + 1]};
      *(float4*)(base + 2 * j2) = v;
    }
  }
}

// Ordering-B sampler: block = 4608 consecutive samp_t flat indices
// (uniform c2,ke2,b2; 24 w2-rows) = exactly 512 whole outputs.
// Wave-uniform skip of fully-OOB taps (sym taps ke2>4 are ~99.8% zero);
// exec-masked per-tap loads (no transactions for OOB lanes).
__global__ __launch_bounds__(576) void sample_kernel(
    const float* __restrict__ x, const float2* __restrict__ off2,
    const float* __restrict__ Wws, const float* __restrict__ bws,
    float* __restrict__ out) {
  __shared__ float buf[4640];  // 4608 + swizzle pad (phys = s + s/144)
  int blk = blockIdx.x, tid = threadIdx.x;
  int c2 = blk / 288;
  int ke2 = (blk / 32) % 9;
  int b2 = (blk / 8) & 3;
  int h2_0 = (blk & 7) * 24;
  int w2 = tid % 192;
  int r0 = tid / 192;
  int td144 = tid % 144;
  int tq144 = tid / 144;
  float wt = Wws[td144];
  const float* xp = x + (size_t)(b2 * CC + c2) * (HH * WW);
  int m = (ke2 < 4) ? ke2 : (ke2 - 5);
  const float2* ob = off2 + (size_t)((c2 * 4 + m) * 4 + b2) * (HH * WW);
  bool hasOff = (ke2 != 4);
  bool neg = (ke2 > 4);
  float yn_base = (float)w2 * (1.0f / 191.0f);
  #pragma unroll
  for (int t8 = 0; t8 < 8; ++t8) {
    int s = t8 * 576 + tid;
    int h2 = h2_0 + 3 * t8 + r0;
    float ox = 0.0f, oy = 0.0f;
    if (hasOff) {
      float2 o = ob[h2 * WW + w2];
      if (neg) { ox = 2.0f - o.x; oy = 2.0f - o.y; }
      else     { ox = o.x;        oy = o.y; }
    }
    float xn = ox + (float)h2 * (1.0f / 191.0f);
    float yn = oy + yn_base;
    float ix = ((xn + 1.0f) * 192.0f - 1.0f) * 0.5f;
    float iy = ((yn + 1.0f) * 192.0f - 1.0f) * 0.5f;
    float val = 0.0f;
    bool in = (ix > -1.0f) && (ix < 192.0f) && (iy > -1.0f) && (iy < 192.0f);
    if (__any(in)) {
      float x0f = floorf(ix), y0f = floorf(iy);
      float fx = ix - x0f, fy = iy - y0f;
      int x0 = (int)x0f, y0 = (int)y0f;
      int x1 = x0 + 1, y1 = y0 + 1;
      bool xi0 = (unsigned)x0 < 192u, xi1 = (unsigned)x1 < 192u;
      bool yi0 = (unsigned)y0 < 192u, yi1 = (unsigned)y1 < 192u;
      float v00 = 0.0f, v01 = 0.0f, v10 = 0.0f, v11 = 0.0f;
      const float* rp0 = xp + y0 * 192;
      const float* rp1 = xp + y1 * 192;
      if (yi0 && xi0) v00 = rp0[x0];
      if (yi0 && xi1) v01 = rp0[x1];
      if (yi1 && xi0) v10 = rp1[x0];
      if (yi1 && xi1) v11 = rp1[x1];
      float sv = v00 * (1.0f - fy) * (1.0f - fx) + v01 * (1.0f - fy) * fx
               + v10 * fy * (1.0f - fx) + v11 * fy * fx;
      val = wt * sv;
    }
    buf[s + t8 * 4 + tq144] = val;  // phys = s + s/144
  }
  __syncthreads();
  if (tid < 512) {
    int wi = tid & 31, c = tid >> 5;
    int o_l = wi * 16 + c;
    int pb = o_l * 9 + (o_l >> 4);  // phys base; lane stride 145 -> conflict-free
    float sum = 0.0f;
    #pragma unroll
    for (int k = 0; k < 9; ++k) sum += buf[pb + k];
    int b = blk / 1152;
    int h = (blk / 6) % 192;
    int w = 32 * (blk % 6) + wi;
    size_t oi = ((size_t)(b * CC + c) * HH + h) * WW + w;
    out[oi] = sum + bws[c] + x[oi];
  }
}

extern "C" void kernel_launch(void* const* d_in, const int* in_sizes, int n_in,
                              void* d_out, int out_size, void* d_ws, size_t ws_size,
                              hipStream_t stream) {
  (void)in_sizes; (void)n_in; (void)out_size; (void)ws_size;
  const float* x    = (const float*)d_in[0];
  const float* Wref = (const float*)d_in[1];
  const float* bref = (const float*)d_in[2];
  const float* Wws  = (const float*)d_in[3];
  const float* bws  = (const float*)d_in[4];
  float* out = (float*)d_out;
  float* Wt  = (float*)d_ws;                          // 73728 B
  float2* off2 = (float2*)((char*)d_ws + 73728);      // 75497472 B

  transpose_w_kernel<<<72, 256, 0, stream>>>(Wref, Wt);
  conv_kernel<<<1152, 256, 0, stream>>>(x, Wt, bref, off2);
  sample_kernel<<<4608, 576, 0, stream>>>(x, off2, Wws, bws, out);
}

// Round 4
// 177.535 us; speedup vs baseline: 1.1818x; 1.1818x over previous
//
#include <hip/hip_runtime.h>

// Seesaw_Conv: 3x3 conv (16->128) offsets -> scrambled bilinear sampling -> 9-tap weighted sum + residual
// B=4, C=16, H=W=192, KE=9, M=4
// ws layout: [0,73728): Wt[144][128]; [73728,+75497472): off pairs float2[64][4][192][192]
//   pair p = c2*4+m holds (off_x, off_y) for channel c2, offset m.

#define HH 192
#define WW 192
#define CC 16
#define CO 128

__global__ __launch_bounds__(256) void transpose_w_kernel(
    const float* __restrict__ Wref, float* __restrict__ Wt) {
  int i = blockIdx.x * 256 + threadIdx.x;
  if (i < CO * 144) {
    int o = i / 144, term = i - o * 144;
    Wt[term * CO + o] = Wref[i];
  }
}

// Direct conv, block = 4h x 64w x 64co, thread = 8w x 8co.
// cin chunked 4x4 -> LDS 15.6 KB -> ~5 blocks/CU (occupancy fix vs R2's 17%).
__global__ __launch_bounds__(256) void conv_kernel(
    const float* __restrict__ x, const float* __restrict__ Wt,
    const float* __restrict__ bref, float2* __restrict__ off2) {
  __shared__ float sW[36][64];    // 9.2 KB (one cin-quad of weights)
  __shared__ float sX[4][6][66];  // 6.3 KB (one cin-quad of x rows)
  int bid = blockIdx.x;
  int ct = bid & 1;
  int wt_ = (bid >> 1) % 3;
  int hp = (bid / 6) % 48;
  int b  = bid / 288;
  int co0 = ct * 64, w0 = wt_ * 64, h0 = hp * 4;
  int t = threadIdx.x;
  int wg = t & 7, cg = (t >> 3) & 7, hr = t >> 6;
  int wl = wg * 8;
  float acc[8][8];  // [w][co]
  #pragma unroll
  for (int j = 0; j < 8; ++j)
    #pragma unroll
    for (int k = 0; k < 8; ++k) acc[j][k] = 0.0f;

  for (int cb = 0; cb < 4; ++cb) {
    __syncthreads();  // previous chunk's reads done
    // stage 36 weight terms x 64 couts, float4
    for (int i = t; i < 36 * 16; i += 256) {
      int tl = i >> 4, c4 = i & 15;
      *(float4*)&sW[tl][c4 * 4] =
          *(const float4*)&Wt[(cb * 36 + tl) * CO + co0 + c4 * 4];
    }
    // stage 4 cin x 6 rows x 66 cols of x (halo, zero-padded)
    for (int i = t; i < 4 * 6 * 66; i += 256) {
      int cin = i / 396;
      int rem = i - cin * 396;
      int r = rem / 66;
      int wl2 = rem - r * 66;
      int gh = h0 + r - 1, gw = w0 + wl2 - 1;
      float v = 0.0f;
      if ((unsigned)gh < 192u && (unsigned)gw < 192u)
        v = x[((b * CC + cb * 4 + cin) * HH + gh) * WW + gw];
      sX[cin][r][wl2] = v;
    }
    __syncthreads();
    #pragma unroll
    for (int ci = 0; ci < 4; ++ci) {
      #pragma unroll
      for (int kh = 0; kh < 3; ++kh) {
        const float* row = &sX[ci][hr + kh][0];
        float4 xa = *(const float4*)&row[wl];
        float4 xb = *(const float4*)&row[wl + 4];
        float2 xc = *(const float2*)&row[wl + 8];
        float xw[10] = {xa.x, xa.y, xa.z, xa.w, xb.x, xb.y, xb.z, xb.w, xc.x, xc.y};
        int term0 = (ci * 3 + kh) * 3;
        #pragma unroll
        for (int kw = 0; kw < 3; ++kw) {
          float4 wa = *(const float4*)&sW[term0 + kw][cg * 8];
          float4 wb = *(const float4*)&sW[term0 + kw][cg * 8 + 4];
          #pragma unroll
          for (int j = 0; j < 8; ++j) {
            float xv = xw[kw + j];
            acc[j][0] += xv * wa.x;  acc[j][1] += xv * wa.y;
            acc[j][2] += xv * wa.z;  acc[j][3] += xv * wa.w;
            acc[j][4] += xv * wb.x;  acc[j][5] += xv * wb.y;
            acc[j][6] += xv * wb.z;  acc[j][7] += xv * wb.w;
          }
        }
      }
    }
  }
  float bias[8];
  #pragma unroll
  for (int i = 0; i < 8; ++i) bias[i] = bref[co0 + cg * 8 + i];
  int h = h0 + hr;
  int p0 = (co0 >> 1) + cg * 4;
  #pragma unroll
  for (int k = 0; k < 4; ++k) {
    float2* base = off2 + ((((size_t)(p0 + k) * 4 + b) * HH + h) * WW + w0 + wl);
    #pragma unroll
    for (int j2 = 0; j2 < 4; ++j2) {
      float4 v = {acc[2 * j2][2 * k] + bias[2 * k], acc[2 * j2][2 * k + 1] + bias[2 * k + 1],
                  acc[2 * j2 + 1][2 * k] + bias[2 * k], acc[2 * j2 + 1][2 * k + 1] + bias[2 * k + 1]};
      *(float4*)(base + 2 * j2) = v;
    }
  }
}

// Ordering-B sampler: block = 4608 consecutive samp_t flat indices
// (uniform c2,ke2,b2; 24 w2-rows) = exactly 512 whole outputs.
// Wave-uniform skip of fully-OOB taps; per-row adjacent-column PAIR loads
// (2 x 8B instead of 4 x 4B -> half the TA tag lookups).
__global__ __launch_bounds__(576) void sample_kernel(
    const float* __restrict__ x, const float2* __restrict__ off2,
    const float* __restrict__ Wws, const float* __restrict__ bws,
    float* __restrict__ out) {
  __shared__ float buf[4640];  // 4608 + swizzle pad (phys = s + s/144)
  int blk = blockIdx.x, tid = threadIdx.x;
  int c2 = blk / 288;
  int ke2 = (blk / 32) % 9;
  int b2 = (blk / 8) & 3;
  int h2_0 = (blk & 7) * 24;
  int w2 = tid % 192;
  int r0 = tid / 192;
  int td144 = tid % 144;
  int tq144 = tid / 144;
  float wt = Wws[td144];
  const float* xp = x + (size_t)(b2 * CC + c2) * (HH * WW);
  int m = (ke2 < 4) ? ke2 : (ke2 - 5);
  const float2* ob = off2 + (size_t)((c2 * 4 + m) * 4 + b2) * (HH * WW);
  bool hasOff = (ke2 != 4);
  bool neg = (ke2 > 4);
  float yn_base = (float)w2 * (1.0f / 191.0f);
  #pragma unroll
  for (int t8 = 0; t8 < 8; ++t8) {
    int s = t8 * 576 + tid;
    int h2 = h2_0 + 3 * t8 + r0;
    float ox = 0.0f, oy = 0.0f;
    if (hasOff) {
      float2 o = ob[h2 * WW + w2];
      if (neg) { ox = 2.0f - o.x; oy = 2.0f - o.y; }
      else     { ox = o.x;        oy = o.y; }
    }
    float xn = ox + (float)h2 * (1.0f / 191.0f);
    float yn = oy + yn_base;
    float ix = ((xn + 1.0f) * 192.0f - 1.0f) * 0.5f;
    float iy = ((yn + 1.0f) * 192.0f - 1.0f) * 0.5f;
    float val = 0.0f;
    bool in = (ix > -1.0f) && (ix < 192.0f) && (iy > -1.0f) && (iy < 192.0f);
    if (__any(in)) {
      float x0f = floorf(ix), y0f = floorf(iy);
      float fx = ix - x0f, fy = iy - y0f;
      int x0 = (int)x0f, y0 = (int)y0f;
      int xb = min(max(x0, 0), 190);
      int y0c = min(max(y0, 0), 191);
      int y1c = min(max(y0 + 1, 0), 191);
      float2 p0, p1;
      __builtin_memcpy(&p0, xp + y0c * 192 + xb, 8);
      __builtin_memcpy(&p1, xp + y1c * 192 + xb, 8);
      bool xlo = (x0 >= 0);
      bool xhi = (x0 + 1 <= 191);
      bool x191 = (x0 == 191);
      float v00 = xlo ? (x191 ? p0.y : p0.x) : 0.0f;
      float v01 = xhi ? (xlo ? p0.y : p0.x) : 0.0f;
      float v10 = xlo ? (x191 ? p1.y : p1.x) : 0.0f;
      float v11 = xhi ? (xlo ? p1.y : p1.x) : 0.0f;
      float r0w = ((unsigned)y0 < 192u) ? (1.0f - fy) : 0.0f;
      float r1w = ((unsigned)(y0 + 1) < 192u) ? fy : 0.0f;
      float sv = r0w * (v00 * (1.0f - fx) + v01 * fx)
               + r1w * (v10 * (1.0f - fx) + v11 * fx);
      val = in ? (wt * sv) : 0.0f;
    }
    buf[s + t8 * 4 + tq144] = val;  // phys = s + s/144
  }
  __syncthreads();
  if (tid < 512) {
    int wi = tid & 31, c = tid >> 5;
    int o_l = wi * 16 + c;
    int pb = o_l * 9 + (o_l >> 4);  // phys base; lane stride 145 -> conflict-free
    float sum = 0.0f;
    #pragma unroll
    for (int k = 0; k < 9; ++k) sum += buf[pb + k];
    int b = blk / 1152;
    int h = (blk / 6) % 192;
    int w = 32 * (blk % 6) + wi;
    size_t oi = ((size_t)(b * CC + c) * HH + h) * WW + w;
    out[oi] = sum + bws[c] + x[oi];
  }
}

extern "C" void kernel_launch(void* const* d_in, const int* in_sizes, int n_in,
                              void* d_out, int out_size, void* d_ws, size_t ws_size,
                              hipStream_t stream) {
  (void)in_sizes; (void)n_in; (void)out_size; (void)ws_size;
  const float* x    = (const float*)d_in[0];
  const float* Wref = (const float*)d_in[1];
  const float* bref = (const float*)d_in[2];
  const float* Wws  = (const float*)d_in[3];
  const float* bws  = (const float*)d_in[4];
  float* out = (float*)d_out;
  float* Wt  = (float*)d_ws;                          // 73728 B
  float2* off2 = (float2*)((char*)d_ws + 73728);      // 75497472 B

  transpose_w_kernel<<<72, 256, 0, stream>>>(Wref, Wt);
  conv_kernel<<<1152, 256, 0, stream>>>(x, Wt, bref, off2);
  sample_kernel<<<4608, 576, 0, stream>>>(x, off2, Wws, bws, out);
}

// Round 6
// 156.208 us; speedup vs baseline: 1.3431x; 1.1365x over previous
//
#include <hip/hip_runtime.h>
#include <hip/hip_fp16.h>

// Seesaw_Conv: 3x3 conv (16->128) offsets -> scrambled bilinear sampling -> 9-tap weighted sum + residual
// B=4, C=16, H=W=192, KE=9, M=4
// ws layout: [0,73728): Wt[144][128]; [73728,+75497472): off pairs float2[64][4][192][192]
// Key fact: output o's 9 samples are positions 9*(o%4096)..+8 of plane (c2,ke2,b2) = o/4096,
// sampled from image (b2,c2). Sampler keeps the whole image in LDS (f16).

#define HH 192
#define WW 192
#define CC 16
#define CO 128
#define IMG_N (HH * WW)  // 36864

__global__ __launch_bounds__(256) void transpose_w_kernel(
    const float* __restrict__ Wref, float* __restrict__ Wt) {
  int i = blockIdx.x * 256 + threadIdx.x;
  if (i < CO * 144) {
    int o = i / 144, term = i - o * 144;
    Wt[term * CO + o] = Wref[i];
  }
}

// Direct conv, block = 4h x 64w x 32co, thread = 8w x 4co, cin chunked 4x4.
// LDS ~11 KB, grid 2304 -> deep occupancy to hide staging latency.
__global__ __launch_bounds__(256) void conv_kernel(
    const float* __restrict__ x, const float* __restrict__ Wt,
    const float* __restrict__ bref, float2* __restrict__ off2) {
  __shared__ float sW[36][32];    // 4.6 KB (one cin-quad of weights, 32 couts)
  __shared__ float sX[4][6][66];  // 6.3 KB
  int bid = blockIdx.x;
  int ct = bid & 3;
  int wt_ = (bid >> 2) % 3;
  int hp = (bid / 12) % 48;
  int b  = bid / 576;
  int co0 = ct * 32, w0 = wt_ * 64, h0 = hp * 4;
  int t = threadIdx.x;
  int wg = t & 7, cg = (t >> 3) & 7, hr = t >> 6;
  int wl = wg * 8;
  float acc[8][4];  // [w][co]
  #pragma unroll
  for (int j = 0; j < 8; ++j)
    #pragma unroll
    for (int k = 0; k < 4; ++k) acc[j][k] = 0.0f;

  for (int cb = 0; cb < 4; ++cb) {
    __syncthreads();
    // stage 36 terms x 8 float4 = 288 float4 (strided: 256 threads!)
    for (int i = t; i < 288; i += 256) {
      int tl = i >> 3, c4 = i & 7;
      *(float4*)&sW[tl][c4 * 4] =
          *(const float4*)&Wt[(cb * 36 + tl) * CO + co0 + c4 * 4];
    }
    for (int i = t; i < 4 * 6 * 66; i += 256) {
      int cin = i / 396;
      int rem = i - cin * 396;
      int r = rem / 66;
      int wl2 = rem - r * 66;
      int gh = h0 + r - 1, gw = w0 + wl2 - 1;
      float v = 0.0f;
      if ((unsigned)gh < 192u && (unsigned)gw < 192u)
        v = x[((b * CC + cb * 4 + cin) * HH + gh) * WW + gw];
      sX[cin][r][wl2] = v;
    }
    __syncthreads();
    #pragma unroll
    for (int ci = 0; ci < 4; ++ci) {
      #pragma unroll
      for (int kh = 0; kh < 3; ++kh) {
        const float* row = &sX[ci][hr + kh][0];
        float4 xa = *(const float4*)&row[wl];
        float4 xb = *(const float4*)&row[wl + 4];
        float2 xc = *(const float2*)&row[wl + 8];
        float xw[10] = {xa.x, xa.y, xa.z, xa.w, xb.x, xb.y, xb.z, xb.w, xc.x, xc.y};
        int term0 = (ci * 3 + kh) * 3;
        #pragma unroll
        for (int kw = 0; kw < 3; ++kw) {
          float4 wa = *(const float4*)&sW[term0 + kw][cg * 4];
          #pragma unroll
          for (int j = 0; j < 8; ++j) {
            float xv = xw[kw + j];
            acc[j][0] += xv * wa.x;  acc[j][1] += xv * wa.y;
            acc[j][2] += xv * wa.z;  acc[j][3] += xv * wa.w;
          }
        }
      }
    }
  }
  float bias[4];
  #pragma unroll
  for (int i = 0; i < 4; ++i) bias[i] = bref[co0 + cg * 4 + i];
  int h = h0 + hr;
  int p0 = (co0 >> 1) + cg * 2;
  #pragma unroll
  for (int k2 = 0; k2 < 2; ++k2) {
    float2* base = off2 + ((((size_t)(p0 + k2) * 4 + b) * HH + h) * WW + w0 + wl);
    #pragma unroll
    for (int j2 = 0; j2 < 4; ++j2) {
      float4 v = {acc[2 * j2][2 * k2] + bias[2 * k2],
                  acc[2 * j2][2 * k2 + 1] + bias[2 * k2 + 1],
                  acc[2 * j2 + 1][2 * k2] + bias[2 * k2],
                  acc[2 * j2 + 1][2 * k2 + 1] + bias[2 * k2 + 1]};
      *(float4*)(base + 2 * j2) = v;
    }
  }
}

// Plane-oriented LDS-image sampler.
// Block = (b2,c2) image + quarter q. LDS: img f16 73728B | offs 73728B | sbuf 4160B.
// Per ke2-plane: thread tid owns output o = plane*4096 + q*1024 + tid (9 in-register taps).
template <int MODE>  // 0 = normal (ke2<4), 1 = sym (ke2>4), 2 = center (ke2==4)
__device__ __forceinline__ void process_plane(
    int ke2, int c2, int b2, int q, int tid, int h2_0, int w2_0,
    const float* wt, const __half* img, const float2* offs, float (*sbuf)[65],
    const float* __restrict__ x, const float* __restrict__ bws,
    float* __restrict__ out) {
  float acc = 0.0f;
  int h2 = h2_0, w2 = w2_0;
  #pragma unroll
  for (int k = 0; k < 9; ++k) {
    float ox = 0.0f, oy = 0.0f;
    if (MODE != 2) {
      float2 o = offs[9 * tid + k];
      if (MODE == 1) { ox = 2.0f - o.x; oy = 2.0f - o.y; }
      else           { ox = o.x;        oy = o.y; }
    }
    float xn = ox + (float)h2 * (1.0f / 191.0f);
    float yn = oy + (float)w2 * (1.0f / 191.0f);
    float ix = xn * 96.0f + 95.5f;
    float iy = yn * 96.0f + 95.5f;
    bool in = (ix > -1.0f) && (ix < 192.0f) && (iy > -1.0f) && (iy < 192.0f);
    bool go = (MODE == 1) ? __any(in) : true;  // sym taps ~99.8% OOB -> wave skip
    if (go) {
      float x0f = floorf(ix), y0f = floorf(iy);
      float fx = ix - x0f, fy = iy - y0f;
      int x0 = (int)x0f, y0 = (int)y0f;
      int x1 = x0 + 1, y1 = y0 + 1;
      bool xi0 = (unsigned)x0 < 192u, xi1 = (unsigned)x1 < 192u;
      bool yi0 = (unsigned)y0 < 192u, yi1 = (unsigned)y1 < 192u;
      int xc0 = min(max(x0, 0), 191), xc1 = min(max(x1, 0), 191);
      int yc0 = min(max(y0, 0), 191), yc1 = min(max(y1, 0), 191);
      float v00 = (yi0 && xi0) ? __half2float(img[yc0 * 192 + xc0]) : 0.0f;
      float v01 = (yi0 && xi1) ? __half2float(img[yc0 * 192 + xc1]) : 0.0f;
      float v10 = (yi1 && xi0) ? __half2float(img[yc1 * 192 + xc0]) : 0.0f;
      float v11 = (yi1 && xi1) ? __half2float(img[yc1 * 192 + xc1]) : 0.0f;
      float sv = v00 * (1.0f - fy) * (1.0f - fx) + v01 * (1.0f - fy) * fx
               + v10 * fy * (1.0f - fx) + v11 * fy * fx;
      acc += wt[k] * sv;
    }
    if (++w2 == 192) { w2 = 0; ++h2; }
  }
  __syncthreads();  // previous plane's sbuf readers done
  sbuf[tid & 15][tid >> 4] = acc;
  __syncthreads();
  int cr = tid >> 6, wl = tid & 63;
  int plane_idx = (c2 * 9 + ke2) * 4 + b2;
  int t16b = plane_idx * 256 + q * 64;
  int w0 = t16b % 192;
  int hb = t16b / 192;
  int h = hb % 192;
  int b = hb / 192;
  size_t addr = ((size_t)(b * 16 + cr) * 192 + h) * 192 + w0 + wl;
  out[addr] = sbuf[cr][wl] + bws[cr] + x[addr];
}

__global__ __launch_bounds__(1024) void sample_kernel(
    const float* __restrict__ x, const float2* __restrict__ off2,
    const float* __restrict__ Wws, const float* __restrict__ bws,
    float* __restrict__ out) {
  extern __shared__ char smem[];
  __half* img = (__half*)smem;                         // 73728 B
  float2* offs = (float2*)(smem + 73728);              // 73728 B
  float (*sbuf)[65] = (float(*)[65])(smem + 147456);   // 4160 B
  int ib = blockIdx.x, tid = threadIdx.x;
  int imgid = ib >> 2, q = ib & 3;
  int b2 = imgid & 3, c2 = imgid >> 2;
  // per-thread output channel weights (same for all planes)
  int c = tid & 15;
  float wt[9];
  #pragma unroll
  for (int k = 0; k < 9; ++k) wt[k] = Wws[c * 9 + k];
  // stage image (f32 -> f16)
  const float4* xs = (const float4*)(x + (size_t)(b2 * CC + c2) * IMG_N);
  #pragma unroll
  for (int j = 0; j < 9; ++j) {
    int i4 = j * 1024 + tid;
    float4 v = xs[i4];
    __half2* ip = (__half2*)img + i4 * 2;
    ip[0] = __floats2half2_rn(v.x, v.y);
    ip[1] = __floats2half2_rn(v.z, v.w);
  }
  int p0 = q * 9216 + 9 * tid;
  int h2_0 = p0 / 192, w2_0 = p0 % 192;
  #pragma unroll 1
  for (int m = 0; m < 4; ++m) {
    __syncthreads();  // img ready / prior plane's offs reads done
    // quarter q = float2 positions [q*9216, (q+1)*9216) = float4 indices [q*4608, ...)
    const float4* ob4 = (const float4*)(off2 + (size_t)((c2 * 4 + m) * 4 + b2) * IMG_N) + q * 4608;
    float4* of4 = (float4*)offs;
    #pragma unroll
    for (int j = 0; j < 4; ++j) of4[j * 1024 + tid] = ob4[j * 1024 + tid];
    if (tid < 512) of4[4096 + tid] = ob4[4096 + tid];
    __syncthreads();
    process_plane<0>(m, c2, b2, q, tid, h2_0, w2_0, wt, img, offs, sbuf, x, bws, out);
    process_plane<1>(m + 5, c2, b2, q, tid, h2_0, w2_0, wt, img, offs, sbuf, x, bws, out);
  }
  process_plane<2>(4, c2, b2, q, tid, h2_0, w2_0, wt, img, offs, sbuf, x, bws, out);
}

extern "C" void kernel_launch(void* const* d_in, const int* in_sizes, int n_in,
                              void* d_out, int out_size, void* d_ws, size_t ws_size,
                              hipStream_t stream) {
  (void)in_sizes; (void)n_in; (void)out_size; (void)ws_size;
  const float* x    = (const float*)d_in[0];
  const float* Wref = (const float*)d_in[1];
  const float* bref = (const float*)d_in[2];
  const float* Wws  = (const float*)d_in[3];
  const float* bws  = (const float*)d_in[4];
  float* out = (float*)d_out;
  float* Wt  = (float*)d_ws;                          // 73728 B
  float2* off2 = (float2*)((char*)d_ws + 73728);      // 75497472 B

  hipFuncSetAttribute(reinterpret_cast<const void*>(sample_kernel),
                      hipFuncAttributeMaxDynamicSharedMemorySize, 151616);
  transpose_w_kernel<<<72, 256, 0, stream>>>(Wref, Wt);
  conv_kernel<<<2304, 256, 0, stream>>>(x, Wt, bref, off2);
  sample_kernel<<<256, 1024, 151616, stream>>>(x, off2, Wws, bws, out);
}

// Round 7
// 150.608 us; speedup vs baseline: 1.3931x; 1.0372x over previous
//
#include <hip/hip_runtime.h>
#include <hip/hip_fp16.h>

// Seesaw_Conv: 3x3 conv (16->128) offsets -> scrambled bilinear sampling -> 9-tap weighted sum + residual
// B=4, C=16, H=W=192, KE=9, M=4
// ws layout: [0,73728): Wpack (f16 hi/lo B-fragments); [73728,+75497472): off2 float2[64][4][192][192]
// Conv = implicit GEMM on MFMA f16 with exact hi/lo split (3 terms), K = taps(9+pad)*cin.

#define HH 192
#define WW 192
#define CC 16
#define CO 128
#define IMG_N (HH * WW)
#define XSTR 10  // dwords per (row,col) cell in packed x-tile (8 cin-pairs + pad, keeps b64 aligned)

typedef _Float16 f16x8 __attribute__((ext_vector_type(8)));
typedef float f32x4 __attribute__((ext_vector_type(4)));
union U4F8 { uint4 u; f16x8 f; };

// Prepack W into MFMA B-fragment order, f16 hi+lo.
// B frag (16x16x32): lane l: co_local = l&15, k = (l>>4)*8 + i; k -> tap_local = (l>>4)>>1, cin = ((l>>4)&1)*8+i.
// Entries: s<4: [(s*8+btg)*64 + l] (taps 2s, 2s+1); s==4: taps (8, zero) -> only l<32 stored at dword 16384.
// Per entry: 8 dwords {hi d0..d3, lo d0..d3}. Total 73728 B.
__global__ __launch_bounds__(256) void prepack_w_kernel(
    const float* __restrict__ Wref, uint* __restrict__ Wpack) {
  int e = blockIdx.x * 256 + threadIdx.x;
  if (e >= 2304) return;
  int s, btg, l;
  if (e < 2048) { s = e >> 9; int rem = e & 511; btg = rem >> 6; l = rem & 63; }
  else { s = 4; int rem = e - 2048; btg = rem >> 5; l = rem & 31; }
  int g = l >> 4;
  int tap = s * 2 + (g >> 1);   // <= 8 here by construction
  int co = btg * 16 + (l & 15);
  int cin0 = (g & 1) * 8;
  int kh = (tap * 11) >> 5;
  int kw = tap - 3 * kh;
  uint hd[4], ld[4];
  #pragma unroll
  for (int j = 0; j < 4; ++j) {
    uint hh[2], ll[2];
    #pragma unroll
    for (int q = 0; q < 2; ++q) {
      int i = 2 * j + q;
      float v = Wref[((co * CC + cin0 + i) * 3 + kh) * 3 + kw];
      __half h = __float2half(v);
      __half lo = __float2half(v - __half2float(h));
      hh[q] = __half_as_ushort(h);
      ll[q] = __half_as_ushort(lo);
    }
    hd[j] = hh[0] | (hh[1] << 16);
    ld[j] = ll[0] | (ll[1] << 16);
  }
  uint base = (e < 2048) ? (uint)e * 8u : 16384u + (uint)(btg * 32 + l) * 8u;
  #pragma unroll
  for (int j = 0; j < 4; ++j) { Wpack[base + j] = hd[j]; Wpack[base + 4 + j] = ld[j]; }
}

// MFMA conv. Block: 2 rows x 64 w x 128 co, 256 thr = 4 waves (wave: r=wv&1, co-half wn=wv>>1).
// x-tile: 4 rows x 66 cols x 16 cin packed as [hi|lo] dwords in XH/XL, stride XSTR.
__global__ __launch_bounds__(256) void conv_kernel(
    const float* __restrict__ x, const uint* __restrict__ Wpack,
    const float* __restrict__ bref, float2* __restrict__ off2) {
  __shared__ uint smem[2 * 2640];  // XH | XL (21120 B); reused as float sb[128*33] in epilogue
  uint* XH = smem;
  uint* XL = smem + 2640;
  int bid = blockIdx.x;
  int wt_ = bid % 3;
  int hp = (bid / 3) % 96;
  int b = bid / 288;
  int w0 = wt_ * 64, h0 = hp * 2;
  int t = threadIdx.x;

  // stage x-tile: 8 cin-pairs x 4 rows x 66 cols, hi/lo split, zero-padded halo
  for (int idx = t; idx < 2112; idx += 256) {
    int cp = idx / 264;
    int rem = idx - cp * 264;
    int row = rem / 66;
    int col = rem - row * 66;
    int gh = h0 + row - 1, gw = w0 + col - 1;
    float v0 = 0.0f, v1 = 0.0f;
    if ((unsigned)gh < 192u && (unsigned)gw < 192u) {
      const float* gp = x + ((size_t)(b * CC + 2 * cp) * HH + gh) * WW + gw;
      v0 = gp[0];
      v1 = gp[IMG_N];
    }
    __half ha = __float2half(v0), hb = __float2half(v1);
    __half la = __float2half(v0 - __half2float(ha));
    __half lb = __float2half(v1 - __half2float(hb));
    int a = (row * 66 + col) * XSTR + cp;
    XH[a] = (uint)__half_as_ushort(ha) | ((uint)__half_as_ushort(hb) << 16);
    XL[a] = (uint)__half_as_ushort(la) | ((uint)__half_as_ushort(lb) << 16);
  }

  int l = t & 63, wv = t >> 6;
  int r = wv & 1, wn = wv >> 1;
  int g = l >> 4, l15 = l & 15;
  int base0 = (r * 66 + l15) * XSTR + (g & 1) * 4;
  int tapl = g >> 1;
  int delta[5];
  #pragma unroll
  for (int s = 0; s < 5; ++s) {
    int tap = s * 2 + tapl;
    if (tap > 8) tap = 8;  // s=4,g>=2: B frag is zero, A reads harmless
    int kh = (tap * 11) >> 5;
    int kw = tap - 3 * kh;
    delta[s] = (kh * 66 + kw) * XSTR;
  }
  f32x4 acc[4][4];
  #pragma unroll
  for (int af = 0; af < 4; ++af)
    #pragma unroll
    for (int bt = 0; bt < 4; ++bt) acc[af][bt] = (f32x4){0.f, 0.f, 0.f, 0.f};

  __syncthreads();

  #pragma unroll
  for (int s = 0; s < 5; ++s) {
    U4F8 bh[4], bl[4];
    #pragma unroll
    for (int bt = 0; bt < 4; ++bt) {
      int btg = wn * 4 + bt;
      if (s < 4) {
        const uint4* bp = (const uint4*)Wpack + ((size_t)((s * 8 + btg) * 64 + l)) * 2;
        bh[bt].u = bp[0];
        bl[bt].u = bp[1];
      } else {
        bh[bt].u = make_uint4(0, 0, 0, 0);
        bl[bt].u = make_uint4(0, 0, 0, 0);
        if (l < 32) {
          const uint4* bp = (const uint4*)Wpack + 4096 + (size_t)(btg * 32 + l) * 2;
          bh[bt].u = bp[0];
          bl[bt].u = bp[1];
        }
      }
    }
    #pragma unroll
    for (int af = 0; af < 4; ++af) {
      int ap = base0 + af * (16 * XSTR) + delta[s];
      uint2 h01 = *(const uint2*)&XH[ap];
      uint2 h23 = *(const uint2*)&XH[ap + 2];
      uint2 l01 = *(const uint2*)&XL[ap];
      uint2 l23 = *(const uint2*)&XL[ap + 2];
      U4F8 ah, al;
      ah.u = make_uint4(h01.x, h01.y, h23.x, h23.y);
      al.u = make_uint4(l01.x, l01.y, l23.x, l23.y);
      #pragma unroll
      for (int bt = 0; bt < 4; ++bt) {
        acc[af][bt] = __builtin_amdgcn_mfma_f32_16x16x32_f16(ah.f, bh[bt].f, acc[af][bt], 0, 0, 0);
        acc[af][bt] = __builtin_amdgcn_mfma_f32_16x16x32_f16(ah.f, bl[bt].f, acc[af][bt], 0, 0, 0);
        acc[af][bt] = __builtin_amdgcn_mfma_f32_16x16x32_f16(al.f, bh[bt].f, acc[af][bt], 0, 0, 0);
      }
    }
  }

  // epilogue: bias + pair-planar coalesced store via LDS transpose (reuses smem)
  float bias[4];
  #pragma unroll
  for (int bt = 0; bt < 4; ++bt) bias[bt] = bref[wn * 64 + bt * 16 + l15];
  float* sb = (float*)smem;
  #pragma unroll 1
  for (int c = 0; c < 4; ++c) {
    __syncthreads();
    if (wn == (c >> 1)) {
      #pragma unroll
      for (int btl = 0; btl < 2; ++btl) {
        int bt = (c & 1) * 2 + btl;
        #pragma unroll
        for (int af = 0; af < 4; ++af)
          #pragma unroll
          for (int reg = 0; reg < 4; ++reg) {
            int px = r * 64 + af * 16 + g * 4 + reg;  // C/D: row=(l>>4)*4+reg, col=l&15
            sb[px * 33 + btl * 16 + l15] = acc[af][bt][reg] + bias[bt];
          }
      }
    }
    __syncthreads();
    int p_l = t >> 4, pxg = t & 15;
    int pair = c * 16 + p_l;
    int rr = pxg >> 3;
    float2* gbase = off2 + ((size_t)(pair * 4 + b) * IMG_N) + (h0 + rr) * WW + w0 + (pxg & 7) * 8;
    #pragma unroll
    for (int e2 = 0; e2 < 4; ++e2) {
      int px = pxg * 8 + e2 * 2;
      float4 v = {sb[px * 33 + 2 * p_l], sb[px * 33 + 2 * p_l + 1],
                  sb[(px + 1) * 33 + 2 * p_l], sb[(px + 1) * 33 + 2 * p_l + 1]};
      *(float4*)(gbase + e2 * 2) = v;
    }
  }
}

// Plane-oriented LDS-image sampler (unchanged from R6, validated).
template <int MODE>  // 0 = normal (ke2<4), 1 = sym (ke2>4), 2 = center (ke2==4)
__device__ __forceinline__ void process_plane(
    int ke2, int c2, int b2, int q, int tid, int h2_0, int w2_0,
    const float* wt, const __half* img, const float2* offs, float (*sbuf)[65],
    const float* __restrict__ x, const float* __restrict__ bws,
    float* __restrict__ out) {
  float acc = 0.0f;
  int h2 = h2_0, w2 = w2_0;
  #pragma unroll
  for (int k = 0; k < 9; ++k) {
    float ox = 0.0f, oy = 0.0f;
    if (MODE != 2) {
      float2 o = offs[9 * tid + k];
      if (MODE == 1) { ox = 2.0f - o.x; oy = 2.0f - o.y; }
      else           { ox = o.x;        oy = o.y; }
    }
    float xn = ox + (float)h2 * (1.0f / 191.0f);
    float yn = oy + (float)w2 * (1.0f / 191.0f);
    float ix = xn * 96.0f + 95.5f;
    float iy = yn * 96.0f + 95.5f;
    bool in = (ix > -1.0f) && (ix < 192.0f) && (iy > -1.0f) && (iy < 192.0f);
    bool go = (MODE == 1) ? __any(in) : true;
    if (go) {
      float x0f = floorf(ix), y0f = floorf(iy);
      float fx = ix - x0f, fy = iy - y0f;
      int x0 = (int)x0f, y0 = (int)y0f;
      int x1 = x0 + 1, y1 = y0 + 1;
      bool xi0 = (unsigned)x0 < 192u, xi1 = (unsigned)x1 < 192u;
      bool yi0 = (unsigned)y0 < 192u, yi1 = (unsigned)y1 < 192u;
      int xc0 = min(max(x0, 0), 191), xc1 = min(max(x1, 0), 191);
      int yc0 = min(max(y0, 0), 191), yc1 = min(max(y1, 0), 191);
      float v00 = (yi0 && xi0) ? __half2float(img[yc0 * 192 + xc0]) : 0.0f;
      float v01 = (yi0 && xi1) ? __half2float(img[yc0 * 192 + xc1]) : 0.0f;
      float v10 = (yi1 && xi0) ? __half2float(img[yc1 * 192 + xc0]) : 0.0f;
      float v11 = (yi1 && xi1) ? __half2float(img[yc1 * 192 + xc1]) : 0.0f;
      float sv = v00 * (1.0f - fy) * (1.0f - fx) + v01 * (1.0f - fy) * fx
               + v10 * fy * (1.0f - fx) + v11 * fy * fx;
      acc += wt[k] * sv;
    }
    if (++w2 == 192) { w2 = 0; ++h2; }
  }
  __syncthreads();
  sbuf[tid & 15][tid >> 4] = acc;
  __syncthreads();
  int cr = tid >> 6, wl = tid & 63;
  int plane_idx = (c2 * 9 + ke2) * 4 + b2;
  int t16b = plane_idx * 256 + q * 64;
  int w0 = t16b % 192;
  int hb = t16b / 192;
  int h = hb % 192;
  int b = hb / 192;
  size_t addr = ((size_t)(b * 16 + cr) * 192 + h) * 192 + w0 + wl;
  out[addr] = sbuf[cr][wl] + bws[cr] + x[addr];
}

__global__ __launch_bounds__(1024) void sample_kernel(
    const float* __restrict__ x, const float2* __restrict__ off2,
    const float* __restrict__ Wws, const float* __restrict__ bws,
    float* __restrict__ out) {
  extern __shared__ char smem[];
  __half* img = (__half*)smem;                         // 73728 B
  float2* offs = (float2*)(smem + 73728);              // 73728 B
  float (*sbuf)[65] = (float(*)[65])(smem + 147456);   // 4160 B
  int ib = blockIdx.x, tid = threadIdx.x;
  int imgid = ib >> 2, q = ib & 3;
  int b2 = imgid & 3, c2 = imgid >> 2;
  int c = tid & 15;
  float wt[9];
  #pragma unroll
  for (int k = 0; k < 9; ++k) wt[k] = Wws[c * 9 + k];
  const float4* xs = (const float4*)(x + (size_t)(b2 * CC + c2) * IMG_N);
  #pragma unroll
  for (int j = 0; j < 9; ++j) {
    int i4 = j * 1024 + tid;
    float4 v = xs[i4];
    __half2* ip = (__half2*)img + i4 * 2;
    ip[0] = __floats2half2_rn(v.x, v.y);
    ip[1] = __floats2half2_rn(v.z, v.w);
  }
  int p0 = q * 9216 + 9 * tid;
  int h2_0 = p0 / 192, w2_0 = p0 % 192;
  #pragma unroll 1
  for (int m = 0; m < 4; ++m) {
    __syncthreads();
    const float4* ob4 = (const float4*)(off2 + (size_t)((c2 * 4 + m) * 4 + b2) * IMG_N) + q * 4608;
    float4* of4 = (float4*)offs;
    #pragma unroll
    for (int j = 0; j < 4; ++j) of4[j * 1024 + tid] = ob4[j * 1024 + tid];
    if (tid < 512) of4[4096 + tid] = ob4[4096 + tid];
    __syncthreads();
    process_plane<0>(m, c2, b2, q, tid, h2_0, w2_0, wt, img, offs, sbuf, x, bws, out);
    process_plane<1>(m + 5, c2, b2, q, tid, h2_0, w2_0, wt, img, offs, sbuf, x, bws, out);
  }
  process_plane<2>(4, c2, b2, q, tid, h2_0, w2_0, wt, img, offs, sbuf, x, bws, out);
}

extern "C" void kernel_launch(void* const* d_in, const int* in_sizes, int n_in,
                              void* d_out, int out_size, void* d_ws, size_t ws_size,
                              hipStream_t stream) {
  (void)in_sizes; (void)n_in; (void)out_size; (void)ws_size;
  const float* x    = (const float*)d_in[0];
  const float* Wref = (const float*)d_in[1];
  const float* bref = (const float*)d_in[2];
  const float* Wws  = (const float*)d_in[3];
  const float* bws  = (const float*)d_in[4];
  float* out = (float*)d_out;
  uint* Wpack = (uint*)d_ws;                           // 73728 B
  float2* off2 = (float2*)((char*)d_ws + 73728);       // 75497472 B

  hipFuncSetAttribute(reinterpret_cast<const void*>(sample_kernel),
                      hipFuncAttributeMaxDynamicSharedMemorySize, 151616);
  prepack_w_kernel<<<9, 256, 0, stream>>>(Wref, Wpack);
  conv_kernel<<<1152, 256, 0, stream>>>(x, Wpack, bref, off2);
  sample_kernel<<<256, 1024, 151616, stream>>>(x, off2, Wws, bws, out);
}

// Round 8
// 113.066 us; speedup vs baseline: 1.8556x; 1.3320x over previous
//
#include <hip/hip_runtime.h>
#include <hip/hip_fp16.h>

// Seesaw_Conv: 3x3 conv (16->128) offsets -> scrambled bilinear sampling -> 9-tap weighted sum + residual
// B=4, C=16, H=W=192, K=3, KE=9, M=4
// ws layout: [0,73728): Wpack (f16 hi/lo B-fragments); [73728,+75497472): off2 float2[64][4][192][192]
// Conv = implicit GEMM on MFMA f16 with exact hi/lo split (3 terms), K = taps(9+pad)*cin.
// R8: co-split blocks (64 co) + named f16x8 frags (bit_cast) to kill the R7 register spill.

#define HH 192
#define WW 192
#define CC 16
#define CO 128
#define IMG_N (HH * WW)
#define XSTR 10  // dwords per (row,col) cell in packed x-tile

typedef _Float16 f16x8 __attribute__((ext_vector_type(8)));
typedef float f32x4 __attribute__((ext_vector_type(4)));
typedef uint u32x4 __attribute__((ext_vector_type(4)));

static __device__ __forceinline__ f16x8 ld_frag_global(const uint* p) {
  u32x4 v = *(const u32x4*)p;
  return __builtin_bit_cast(f16x8, v);
}

// Prepack W into MFMA B-fragment order, f16 hi+lo. (validated in R7)
__global__ __launch_bounds__(256) void prepack_w_kernel(
    const float* __restrict__ Wref, uint* __restrict__ Wpack) {
  int e = blockIdx.x * 256 + threadIdx.x;
  if (e >= 2304) return;
  int s, btg, l;
  if (e < 2048) { s = e >> 9; int rem = e & 511; btg = rem >> 6; l = rem & 63; }
  else { s = 4; int rem = e - 2048; btg = rem >> 5; l = rem & 31; }
  int g = l >> 4;
  int tap = s * 2 + (g >> 1);
  int co = btg * 16 + (l & 15);
  int cin0 = (g & 1) * 8;
  int kh = (tap * 11) >> 5;
  int kw = tap - 3 * kh;
  uint hd[4], ld[4];
  #pragma unroll
  for (int j = 0; j < 4; ++j) {
    uint hh[2], ll[2];
    #pragma unroll
    for (int q = 0; q < 2; ++q) {
      int i = 2 * j + q;
      float v = Wref[((co * CC + cin0 + i) * 3 + kh) * 3 + kw];
      __half h = __float2half(v);
      __half lo = __float2half(v - __half2float(h));
      hh[q] = __half_as_ushort(h);
      ll[q] = __half_as_ushort(lo);
    }
    hd[j] = hh[0] | (hh[1] << 16);
    ld[j] = ll[0] | (ll[1] << 16);
  }
  uint base = (e < 2048) ? (uint)e * 8u : 16384u + (uint)(btg * 32 + l) * 8u;
  #pragma unroll
  for (int j = 0; j < 4; ++j) { Wpack[base + j] = hd[j]; Wpack[base + 4 + j] = ld[j]; }
}

// MFMA conv. Block: 2 rows x 64 w x 64 co, 256 thr = 4 waves (r = wv&1, co-32-half wn = wv>>1).
__global__ __launch_bounds__(256) void conv_kernel(
    const float* __restrict__ x, const uint* __restrict__ Wpack,
    const float* __restrict__ bref, float2* __restrict__ off2) {
  __shared__ uint smem[2 * 2640];  // XH | XL (21120 B); epilogue reuse: float sb[128*33]
  uint* XH = smem;
  uint* XL = smem + 2640;
  int bid = blockIdx.x;
  int cblk = bid & 1;              // co 64-half
  int wt_ = (bid >> 1) % 3;
  int hp = (bid / 6) % 96;
  int b = bid / 576;
  int w0 = wt_ * 64, h0 = hp * 2;
  int t = threadIdx.x;

  // stage x-tile: 8 cin-pairs x 4 rows x 66 cols, hi/lo split, zero-padded halo
  for (int idx = t; idx < 2112; idx += 256) {
    int cp = idx / 264;
    int rem = idx - cp * 264;
    int row = rem / 66;
    int col = rem - row * 66;
    int gh = h0 + row - 1, gw = w0 + col - 1;
    float v0 = 0.0f, v1 = 0.0f;
    if ((unsigned)gh < 192u && (unsigned)gw < 192u) {
      const float* gp = x + ((size_t)(b * CC + 2 * cp) * HH + gh) * WW + gw;
      v0 = gp[0];
      v1 = gp[IMG_N];
    }
    __half ha = __float2half(v0), hb = __float2half(v1);
    __half la = __float2half(v0 - __half2float(ha));
    __half lb = __float2half(v1 - __half2float(hb));
    int a = (row * 66 + col) * XSTR + cp;
    XH[a] = (uint)__half_as_ushort(ha) | ((uint)__half_as_ushort(hb) << 16);
    XL[a] = (uint)__half_as_ushort(la) | ((uint)__half_as_ushort(lb) << 16);
  }

  int l = t & 63, wv = t >> 6;
  int r = wv & 1, wn = wv >> 1;
  int g = l >> 4, l15 = l & 15;
  int base0 = (r * 66 + l15) * XSTR + (g & 1) * 4;
  int tapl = g >> 1;
  int btg0 = cblk * 4 + wn * 2;
  f32x4 acc[4][2];
  #pragma unroll
  for (int af = 0; af < 4; ++af)
    #pragma unroll
    for (int bt = 0; bt < 2; ++bt) acc[af][bt] = (f32x4){0.f, 0.f, 0.f, 0.f};

  __syncthreads();

  #pragma unroll 1
  for (int s = 0; s < 5; ++s) {
    u32x4 z4 = {0, 0, 0, 0};
    f16x8 bh0 = __builtin_bit_cast(f16x8, z4), bl0 = bh0, bh1 = bh0, bl1 = bh0;
    if (s < 4) {
      const uint* bp0 = Wpack + (size_t)((s * 8 + btg0) * 64 + l) * 8;
      bh0 = ld_frag_global(bp0);
      bl0 = ld_frag_global(bp0 + 4);
      const uint* bp1 = Wpack + (size_t)((s * 8 + btg0 + 1) * 64 + l) * 8;
      bh1 = ld_frag_global(bp1);
      bl1 = ld_frag_global(bp1 + 4);
    } else if (l < 32) {
      const uint* bp0 = Wpack + 16384 + (size_t)(btg0 * 32 + l) * 8;
      bh0 = ld_frag_global(bp0);
      bl0 = ld_frag_global(bp0 + 4);
      const uint* bp1 = Wpack + 16384 + (size_t)((btg0 + 1) * 32 + l) * 8;
      bh1 = ld_frag_global(bp1);
      bl1 = ld_frag_global(bp1 + 4);
    }
    int tap = s * 2 + tapl;
    if (tap > 8) tap = 8;  // pad tap: B frag zero, A read harmless
    int kh = (tap * 11) >> 5;
    int kw = tap - 3 * kh;
    int delta = (kh * 66 + kw) * XSTR;
    #pragma unroll
    for (int af = 0; af < 4; ++af) {
      int ap = base0 + af * (16 * XSTR) + delta;
      uint2 h01 = *(const uint2*)&XH[ap];
      uint2 h23 = *(const uint2*)&XH[ap + 2];
      uint2 l01 = *(const uint2*)&XL[ap];
      uint2 l23 = *(const uint2*)&XL[ap + 2];
      u32x4 th = {h01.x, h01.y, h23.x, h23.y};
      u32x4 tl = {l01.x, l01.y, l23.x, l23.y};
      f16x8 ah = __builtin_bit_cast(f16x8, th);
      f16x8 al = __builtin_bit_cast(f16x8, tl);
      acc[af][0] = __builtin_amdgcn_mfma_f32_16x16x32_f16(ah, bh0, acc[af][0], 0, 0, 0);
      acc[af][0] = __builtin_amdgcn_mfma_f32_16x16x32_f16(ah, bl0, acc[af][0], 0, 0, 0);
      acc[af][0] = __builtin_amdgcn_mfma_f32_16x16x32_f16(al, bh0, acc[af][0], 0, 0, 0);
      acc[af][1] = __builtin_amdgcn_mfma_f32_16x16x32_f16(ah, bh1, acc[af][1], 0, 0, 0);
      acc[af][1] = __builtin_amdgcn_mfma_f32_16x16x32_f16(ah, bl1, acc[af][1], 0, 0, 0);
      acc[af][1] = __builtin_amdgcn_mfma_f32_16x16x32_f16(al, bh1, acc[af][1], 0, 0, 0);
    }
  }

  // epilogue: bias + pair-planar coalesced store via LDS transpose (reuses smem)
  float bias[2];
  #pragma unroll
  for (int bt = 0; bt < 2; ++bt) bias[bt] = bref[cblk * 64 + wn * 32 + bt * 16 + l15];
  float* sb = (float*)smem;  // [128 px][33], holds 32 co (one wn-half)
  #pragma unroll 1
  for (int c = 0; c < 2; ++c) {
    __syncthreads();
    if (wn == c) {
      #pragma unroll
      for (int bt = 0; bt < 2; ++bt)
        #pragma unroll
        for (int af = 0; af < 4; ++af)
          #pragma unroll
          for (int reg = 0; reg < 4; ++reg) {
            int px = r * 64 + af * 16 + g * 4 + reg;  // C/D: row=(l>>4)*4+reg, col=l&15
            sb[px * 33 + bt * 16 + l15] = acc[af][bt][reg] + bias[bt];
          }
    }
    __syncthreads();
    int p_l = t >> 4, pxg = t & 15;
    int pair = cblk * 32 + c * 16 + p_l;
    int rr = pxg >> 3;
    float2* gbase = off2 + ((size_t)(pair * 4 + b) * IMG_N) + (h0 + rr) * WW + w0 + (pxg & 7) * 8;
    #pragma unroll
    for (int e2 = 0; e2 < 4; ++e2) {
      int px = pxg * 8 + e2 * 2;
      float4 v = {sb[px * 33 + 2 * p_l], sb[px * 33 + 2 * p_l + 1],
                  sb[(px + 1) * 33 + 2 * p_l], sb[(px + 1) * 33 + 2 * p_l + 1]};
      *(float4*)(gbase + e2 * 2) = v;
    }
  }
}

// Plane-oriented LDS-image sampler (unchanged, validated).
template <int MODE>  // 0 = normal (ke2<4), 1 = sym (ke2>4), 2 = center (ke2==4)
__device__ __forceinline__ void process_plane(
    int ke2, int c2, int b2, int q, int tid, int h2_0, int w2_0,
    const float* wt, const __half* img, const float2* offs, float (*sbuf)[65],
    const float* __restrict__ x, const float* __restrict__ bws,
    float* __restrict__ out) {
  float acc = 0.0f;
  int h2 = h2_0, w2 = w2_0;
  #pragma unroll
  for (int k = 0; k < 9; ++k) {
    float ox = 0.0f, oy = 0.0f;
    if (MODE != 2) {
      float2 o = offs[9 * tid + k];
      if (MODE == 1) { ox = 2.0f - o.x; oy = 2.0f - o.y; }
      else           { ox = o.x;        oy = o.y; }
    }
    float xn = ox + (float)h2 * (1.0f / 191.0f);
    float yn = oy + (float)w2 * (1.0f / 191.0f);
    float ix = xn * 96.0f + 95.5f;
    float iy = yn * 96.0f + 95.5f;
    bool in = (ix > -1.0f) && (ix < 192.0f) && (iy > -1.0f) && (iy < 192.0f);
    bool go = (MODE == 1) ? __any(in) : true;
    if (go) {
      float x0f = floorf(ix), y0f = floorf(iy);
      float fx = ix - x0f, fy = iy - y0f;
      int x0 = (int)x0f, y0 = (int)y0f;
      int x1 = x0 + 1, y1 = y0 + 1;
      bool xi0 = (unsigned)x0 < 192u, xi1 = (unsigned)x1 < 192u;
      bool yi0 = (unsigned)y0 < 192u, yi1 = (unsigned)y1 < 192u;
      int xc0 = min(max(x0, 0), 191), xc1 = min(max(x1, 0), 191);
      int yc0 = min(max(y0, 0), 191), yc1 = min(max(y1, 0), 191);
      float v00 = (yi0 && xi0) ? __half2float(img[yc0 * 192 + xc0]) : 0.0f;
      float v01 = (yi0 && xi1) ? __half2float(img[yc0 * 192 + xc1]) : 0.0f;
      float v10 = (yi1 && xi0) ? __half2float(img[yc1 * 192 + xc0]) : 0.0f;
      float v11 = (yi1 && xi1) ? __half2float(img[yc1 * 192 + xc1]) : 0.0f;
      float sv = v00 * (1.0f - fy) * (1.0f - fx) + v01 * (1.0f - fy) * fx
               + v10 * fy * (1.0f - fx) + v11 * fy * fx;
      acc += wt[k] * sv;
    }
    if (++w2 == 192) { w2 = 0; ++h2; }
  }
  __syncthreads();
  sbuf[tid & 15][tid >> 4] = acc;
  __syncthreads();
  int cr = tid >> 6, wl = tid & 63;
  int plane_idx = (c2 * 9 + ke2) * 4 + b2;
  int t16b = plane_idx * 256 + q * 64;
  int w0 = t16b % 192;
  int hb = t16b / 192;
  int h = hb % 192;
  int b = hb / 192;
  size_t addr = ((size_t)(b * 16 + cr) * 192 + h) * 192 + w0 + wl;
  out[addr] = sbuf[cr][wl] + bws[cr] + x[addr];
}

__global__ __launch_bounds__(1024) void sample_kernel(
    const float* __restrict__ x, const float2* __restrict__ off2,
    const float* __restrict__ Wws, const float* __restrict__ bws,
    float* __restrict__ out) {
  extern __shared__ char smem[];
  __half* img = (__half*)smem;                         // 73728 B
  float2* offs = (float2*)(smem + 73728);              // 73728 B
  float (*sbuf)[65] = (float(*)[65])(smem + 147456);   // 4160 B
  int ib = blockIdx.x, tid = threadIdx.x;
  int imgid = ib >> 2, q = ib & 3;
  int b2 = imgid & 3, c2 = imgid >> 2;
  int c = tid & 15;
  float wt[9];
  #pragma unroll
  for (int k = 0; k < 9; ++k) wt[k] = Wws[c * 9 + k];
  const float4* xs = (const float4*)(x + (size_t)(b2 * CC + c2) * IMG_N);
  #pragma unroll
  for (int j = 0; j < 9; ++j) {
    int i4 = j * 1024 + tid;
    float4 v = xs[i4];
    __half2* ip = (__half2*)img + i4 * 2;
    ip[0] = __floats2half2_rn(v.x, v.y);
    ip[1] = __floats2half2_rn(v.z, v.w);
  }
  int p0 = q * 9216 + 9 * tid;
  int h2_0 = p0 / 192, w2_0 = p0 % 192;
  #pragma unroll 1
  for (int m = 0; m < 4; ++m) {
    __syncthreads();
    const float4* ob4 = (const float4*)(off2 + (size_t)((c2 * 4 + m) * 4 + b2) * IMG_N) + q * 4608;
    float4* of4 = (float4*)offs;
    #pragma unroll
    for (int j = 0; j < 4; ++j) of4[j * 1024 + tid] = ob4[j * 1024 + tid];
    if (tid < 512) of4[4096 + tid] = ob4[4096 + tid];
    __syncthreads();
    process_plane<0>(m, c2, b2, q, tid, h2_0, w2_0, wt, img, offs, sbuf, x, bws, out);
    process_plane<1>(m + 5, c2, b2, q, tid, h2_0, w2_0, wt, img, offs, sbuf, x, bws, out);
  }
  process_plane<2>(4, c2, b2, q, tid, h2_0, w2_0, wt, img, offs, sbuf, x, bws, out);
}

extern "C" void kernel_launch(void* const* d_in, const int* in_sizes, int n_in,
                              void* d_out, int out_size, void* d_ws, size_t ws_size,
                              hipStream_t stream) {
  (void)in_sizes; (void)n_in; (void)out_size; (void)ws_size;
  const float* x    = (const float*)d_in[0];
  const float* Wref = (const float*)d_in[1];
  const float* bref = (const float*)d_in[2];
  const float* Wws  = (const float*)d_in[3];
  const float* bws  = (const float*)d_in[4];
  float* out = (float*)d_out;
  uint* Wpack = (uint*)d_ws;                           // 73728 B
  float2* off2 = (float2*)((char*)d_ws + 73728);       // 75497472 B

  hipFuncSetAttribute(reinterpret_cast<const void*>(sample_kernel),
                      hipFuncAttributeMaxDynamicSharedMemorySize, 151616);
  prepack_w_kernel<<<9, 256, 0, stream>>>(Wref, Wpack);
  conv_kernel<<<2304, 256, 0, stream>>>(x, Wpack, bref, off2);
  sample_kernel<<<256, 1024, 151616, stream>>>(x, off2, Wws, bws, out);
}